// Round 2
// baseline (18172.040 us; speedup 1.0000x reference)
//
#include <hip/hip_runtime.h>
#include <cstdint>

// ---------------------------------------------------------------------------
// SC-LSTM persistent kernel, MI355X (gfx950) — round 2.
//
//  * Split-precision fp16 MFMA GEMM: every operand stored as (hi, lo) fp16
//    pair; D = Ah*Bh + Ah*Bl + Al*Bh accumulated in fp32 -> ~2^-22 operand
//    precision, fixes round-1's 5.15e-2 absmax (fp16 quant random walk).
//  * Grid = 71 blocks: 64 gate blocks (4 col-tiles = 16 hcols each) +
//    7 reading-gate blocks (16 r-cols each). Minimizes per-block A-operand
//    replication traffic (384KB/block/step).
//  * No acquire fences (would evict L2-resident weights every step).
//    Cross-block data (hbuf, dws) is read with agent-scope atomic loads
//    (sc-bypass, coherent from MALL); producers publish via RELEASE
//    fetch_add on monotone counters (wbl2 flush). One full barrier/step +
//    one producer-consumer d-counter wait.
//  * d@Wd (K=100 padded to 128) also via split MFMA, 12 MFMAs/wave/step.
// ---------------------------------------------------------------------------

#define TT    256
#define BB    64
#define IC    512
#define HC    1024
#define DC    100
#define KC    1536
#define NG    4096
#define KSTEP 48      // KC/32
#define NTILE 263     // 256 gate tiles + 7 r tiles
#define NGB   64      // gate blocks
#define NRB   7       // r blocks
#define NBLK  (NGB + NRB)
#define NTHR  256

typedef _Float16 f16;
typedef f16   f16x8 __attribute__((ext_vector_type(8)));
typedef float f32x4 __attribute__((ext_vector_type(4)));
typedef unsigned long long u64;

// ---- workspace layout (bytes) ----
#define WS_BAR   0ull                      // 256 B: [0]=dcnt [1]=cnt
#define WS_XH    256ull                    // fp16 T*B*I        = 16,777,216 B
#define WS_XL    (WS_XH  + 16777216ull)
#define WS_BPH   (WS_XL  + 16777216ull)    // fp16 263*48*512   = 12,926,976 B
#define WS_BPL   (WS_BPH + 12926976ull)
#define WS_WDFH  (WS_BPL + 12926976ull)    // fp16 64*4*512     = 262,144 B
#define WS_WDFL  (WS_WDFH + 262144ull)
#define WS_HBH   (WS_WDFL + 262144ull)     // fp16 2*B*H        = 262,144 B
#define WS_HBL   (WS_HBH + 262144ull)
#define WS_DW    (WS_HBL + 262144ull)      // fp32 2*B*D        = 51,200 B
// end = WS_DW + 51200 = 60,508,416 B (~57.7 MB)

// ------------------------------------------------------------- prep kernels

__global__ void prep_x(const float* __restrict__ x, f16* __restrict__ xh,
                       f16* __restrict__ xl, int nq) {
    int i = (blockIdx.x * blockDim.x + threadIdx.x) * 4;
    if (i < nq) {
        float4 v = *(const float4*)(x + i);
        f16 h0 = (f16)v.x, h1 = (f16)v.y, h2 = (f16)v.z, h3 = (f16)v.w;
        f16 vh[4] = {h0, h1, h2, h3};
        f16 vl[4] = {(f16)(v.x - (float)h0), (f16)(v.y - (float)h1),
                     (f16)(v.z - (float)h2), (f16)(v.w - (float)h3)};
        *(f16x8*)0; // (unused)
        *(short4*)(xh + i) = *(short4*)vh;
        *(short4*)(xl + i) = *(short4*)vl;
    }
}

__global__ void prep_B(const float* __restrict__ Wx, const float* __restrict__ Wh,
                       const float* __restrict__ Wrx, const float* __restrict__ Wrh,
                       f16* __restrict__ Bph, f16* __restrict__ Bpl) {
    const int tile = blockIdx.x / KSTEP;
    const int ks   = blockIdx.x % KSTEP;
    const int lane = threadIdx.x;
    const int n    = lane & 15;
    const int quad = lane >> 4;
    f16 vh[8], vl[8];
#pragma unroll
    for (int j = 0; j < 8; ++j) {
        const int k = ks * 32 + quad * 8 + j;
        float s;
        if (tile < 256) {
            const int gcol = (n >> 2) * HC + tile * 4 + (n & 3);
            s = (k < IC) ? Wx[(size_t)k * NG + gcol] : Wh[(size_t)(k - IC) * NG + gcol];
        } else {
            const int rk = (tile - 256) * 16 + n;
            if (rk < DC) s = (k < IC) ? Wrx[(size_t)k * DC + rk] : 0.5f * Wrh[(size_t)(k - IC) * DC + rk];
            else         s = 0.0f;
        }
        f16 hi = (f16)s;
        vh[j] = hi;
        vl[j] = (f16)(s - (float)hi);
    }
    const size_t base = ((size_t)blockIdx.x * 64 + lane) * 8;
    *(f16x8*)(Bph + base) = *(f16x8*)vh;
    *(f16x8*)(Bpl + base) = *(f16x8*)vl;
}

__global__ void prep_Wd(const float* __restrict__ Wd, f16* __restrict__ WdFh,
                        f16* __restrict__ WdFl) {
    const int tile = blockIdx.x >> 2;    // 0..63
    const int ks   = blockIdx.x & 3;     // 0..3
    const int lane = threadIdx.x;
    const int n    = lane & 15;
    const int quad = lane >> 4;
    f16 vh[8], vl[8];
#pragma unroll
    for (int j = 0; j < 8; ++j) {
        const int k = ks * 32 + quad * 8 + j;     // 0..127
        const int col = tile * 16 + n;
        float s = (k < DC) ? Wd[(size_t)k * HC + col] : 0.0f;
        f16 hi = (f16)s;
        vh[j] = hi;
        vl[j] = (f16)(s - (float)hi);
    }
    const size_t base = ((size_t)blockIdx.x * 64 + lane) * 8;
    *(f16x8*)(WdFh + base) = *(f16x8*)vh;
    *(f16x8*)(WdFl + base) = *(f16x8*)vl;
}

__global__ void prep_misc(const float* __restrict__ h0, f16* __restrict__ hbh,
                          f16* __restrict__ hbl, const float* __restrict__ d0,
                          float* __restrict__ dws, unsigned* __restrict__ bar) {
    const int i = blockIdx.x * blockDim.x + threadIdx.x;
    if (i < BB * HC) {
        float v = h0[i];
        f16 hi = (f16)v;
        hbh[i] = hi;
        hbl[i] = (f16)(v - (float)hi);
    }
    if (i < BB * DC) dws[i] = d0[i];
    if (i < 8) bar[i] = 0u;
}

// ------------------------------------------------------------- device utils

__device__ __forceinline__ float fast_sigmoid(float x) {
    return 1.0f / (1.0f + __expf(-x));
}
__device__ __forceinline__ float fast_tanh(float x) {
    float ax = fabsf(x);
    float e  = __expf(-2.0f * ax);
    float r  = (1.0f - e) / (1.0f + e);
    return copysignf(r, x);
}

// coherent (agent-scope, L2-bypassing) 16B load as 2x b64 atomics
__device__ __forceinline__ f16x8 aload16(const f16* p) {
    union { u64 q[2]; f16x8 v; } u;
    u.q[0] = __hip_atomic_load((const u64*)p, __ATOMIC_RELAXED, __HIP_MEMORY_SCOPE_AGENT);
    u.q[1] = __hip_atomic_load(((const u64*)p) + 1, __ATOMIC_RELAXED, __HIP_MEMORY_SCOPE_AGENT);
    return u.v;
}

// coherent 8B fp32-pair load
__device__ __forceinline__ float2 aload8f(const float* p) {
    union { u64 q; float2 f; } u;
    u.q = __hip_atomic_load((const u64*)p, __ATOMIC_RELAXED, __HIP_MEMORY_SCOPE_AGENT);
    return u.f;
}

template <int NT>
__device__ __forceinline__ void gemm_tiles(const f16* __restrict__ xh, const f16* __restrict__ xl,
                                           const f16* hh, const f16* hl,
                                           const f16* __restrict__ bh, const f16* __restrict__ bl,
                                           f32x4* acc) {
#pragma unroll
    for (int ks = 0; ks < KSTEP; ++ks) {
        f16x8 ah, al;
        if (ks < 16) {           // x part, K 0..511 (normal cached loads)
            ah = *(const f16x8*)(xh + ks * 32);
            al = *(const f16x8*)(xl + ks * 32);
        } else {                 // h part, K 512..1535 (coherent loads)
            ah = aload16(hh + (ks - 16) * 32);
            al = aload16(hl + (ks - 16) * 32);
        }
        f16x8 wh[NT], wl[NT];
#pragma unroll
        for (int tl = 0; tl < NT; ++tl) {
            wh[tl] = *(const f16x8*)(bh + (size_t)(tl * KSTEP + ks) * 512);
            wl[tl] = *(const f16x8*)(bl + (size_t)(tl * KSTEP + ks) * 512);
        }
#pragma unroll
        for (int tl = 0; tl < NT; ++tl)
            acc[tl] = __builtin_amdgcn_mfma_f32_16x16x32_f16(ah, wh[tl], acc[tl], 0, 0, 0);
#pragma unroll
        for (int tl = 0; tl < NT; ++tl)
            acc[tl] = __builtin_amdgcn_mfma_f32_16x16x32_f16(ah, wl[tl], acc[tl], 0, 0, 0);
#pragma unroll
        for (int tl = 0; tl < NT; ++tl)
            acc[tl] = __builtin_amdgcn_mfma_f32_16x16x32_f16(al, wh[tl], acc[tl], 0, 0, 0);
    }
}

// ------------------------------------------------------------- main kernel

__global__ __launch_bounds__(NTHR) void sclstm_main(
    const f16* __restrict__ x2h, const f16* __restrict__ x2l,
    const f16* __restrict__ Bph, const f16* __restrict__ Bpl,
    const f16* __restrict__ WdFh, const f16* __restrict__ WdFl,
    f16* hbh, f16* hbl, float* dws,
    const float* __restrict__ bvec, const float* __restrict__ c0,
    float* __restrict__ out, unsigned* bar) {

    const int bid  = blockIdx.x;
    const int tid  = threadIdx.x;
    const int w    = tid >> 6;
    const int lane = tid & 63;
    const int n    = lane & 15;
    const int quad = lane >> 4;
    const int brow = w * 16 + n;            // A-fragment batch row

    __shared__ float gl[BB][68];            // gate preacts, padded stride

    unsigned* dcnt = bar;                   // monotone: +7 per step
    unsigned* cnt  = bar + 1;               // monotone: +NBLK per step

    if (bid < NGB) {
        // ------------------------- gate block: 16 hcols = tiles 4g..4g+3
        const int g = bid;
        float bias[4];
#pragma unroll
        for (int tl = 0; tl < 4; ++tl)
            bias[tl] = bvec[(n >> 2) * HC + g * 16 + tl * 4 + (n & 3)];

        const int crow = w * 16 + quad * 4;   // c-rows crow..crow+3
        const int ccol = g * 16 + n;          // c-col (global hcol)
        float c[4];
#pragma unroll
        for (int r = 0; r < 4; ++r) c[r] = c0[(size_t)(crow + r) * HC + ccol];

        const f16* bh   = Bph + (size_t)(4 * g) * KSTEP * 512 + lane * 8;
        const f16* bl   = Bpl + (size_t)(4 * g) * KSTEP * 512 + lane * 8;
        const f16* wdfh = WdFh + (size_t)g * 4 * 512 + lane * 8;
        const f16* wdfl = WdFl + (size_t)g * 4 * 512 + lane * 8;

        for (int t = 0; t < TT; ++t) {
            const int cur = t & 1, nxt = cur ^ 1;

            // ---- phase 1: gate GEMM (4 tiles, split precision) ----
            const f16* xh = x2h + ((size_t)t * BB + brow) * IC + quad * 8;
            const f16* xl = x2l + ((size_t)t * BB + brow) * IC + quad * 8;
            const f16* hh = hbh + (size_t)cur * BB * HC + (size_t)brow * HC + quad * 8;
            const f16* hl = hbl + (size_t)cur * BB * HC + (size_t)brow * HC + quad * 8;
            f32x4 acc[4] = {{0,0,0,0},{0,0,0,0},{0,0,0,0},{0,0,0,0}};
            gemm_tiles<4>(xh, xl, hh, hl, bh, bl, acc);

            // epilogue -> LDS (C/D layout: col=lane&15, row=quad*4+reg)
#pragma unroll
            for (int tl = 0; tl < 4; ++tl)
#pragma unroll
                for (int r = 0; r < 4; ++r)
                    gl[w * 16 + quad * 4 + r][tl * 16 + n] = acc[tl][r] + bias[tl];

            // ---- wait for d_new (produced by r-blocks) ----
            if (tid == 0) {
                const unsigned tgt = 7u * (t + 1);
                while (__hip_atomic_load(dcnt, __ATOMIC_RELAXED, __HIP_MEMORY_SCOPE_AGENT) < tgt)
                    __builtin_amdgcn_s_sleep(1);
            }
            __syncthreads();

            // ---- phase 2a: dwd = tanh-arg = d_new @ Wd  (split MFMA, K=128 padded)
            f32x4 da = {0, 0, 0, 0};
            const float* dptr = dws + (size_t)nxt * BB * DC + (size_t)brow * DC;
#pragma unroll
            for (int ks = 0; ks < 4; ++ks) {
                const int kbase = ks * 32 + quad * 8;
                f16 dh[8], dl[8];
#pragma unroll
                for (int j2 = 0; j2 < 4; ++j2) {
                    const int k = kbase + 2 * j2;
                    float2 v = {0.f, 0.f};
                    if (k < DC) v = aload8f(dptr + k);
                    f16 h0 = (f16)v.x, h1 = (f16)v.y;
                    dh[2 * j2] = h0;     dl[2 * j2] = (f16)(v.x - (float)h0);
                    dh[2 * j2 + 1] = h1; dl[2 * j2 + 1] = (f16)(v.y - (float)h1);
                }
                f16x8 dhv = *(f16x8*)dh, dlv = *(f16x8*)dl;
                f16x8 uh = *(const f16x8*)(wdfh + (size_t)ks * 512);
                f16x8 ul = *(const f16x8*)(wdfl + (size_t)ks * 512);
                da = __builtin_amdgcn_mfma_f32_16x16x32_f16(dhv, uh, da, 0, 0, 0);
                da = __builtin_amdgcn_mfma_f32_16x16x32_f16(dhv, ul, da, 0, 0, 0);
                da = __builtin_amdgcn_mfma_f32_16x16x32_f16(dlv, uh, da, 0, 0, 0);
            }

            // ---- phase 2b: c/h update (4 states/thread) ----
#pragma unroll
            for (int r = 0; r < 4; ++r) {
                const int row = crow + r;
                const int cb  = (n >> 2) * 16 + (n & 3);
                const float iv = fast_sigmoid(gl[row][cb + 0]);
                const float fv = fast_sigmoid(gl[row][cb + 4]);
                const float gv = fast_tanh(gl[row][cb + 8]);
                const float ov = fast_sigmoid(gl[row][cb + 12]);
                c[r] = fv * c[r] + iv * gv + fast_tanh(da[r]);
                const float h = ov * fast_tanh(c[r]);
                out[((size_t)t * BB + row) * HC + ccol] = h;
                const f16 hi = (f16)h;
                hbh[(size_t)nxt * BB * HC + (size_t)row * HC + ccol] = hi;
                hbl[(size_t)nxt * BB * HC + (size_t)row * HC + ccol] = (f16)(h - (float)hi);
                if (t == TT - 1) {
                    out[(size_t)TT * BB * HC + (size_t)row * HC + ccol] = h;
                    out[(size_t)TT * BB * HC + BB * HC + (size_t)row * HC + ccol] = c[r];
                }
            }

            // ---- full barrier: publish h ----
            __syncthreads();                          // drains vmcnt for all waves
            if (tid == 0) {
                __hip_atomic_fetch_add(cnt, 1u, __ATOMIC_RELEASE, __HIP_MEMORY_SCOPE_AGENT);
                const unsigned tgt = (unsigned)NBLK * (t + 1);
                while (__hip_atomic_load(cnt, __ATOMIC_RELAXED, __HIP_MEMORY_SCOPE_AGENT) < tgt)
                    __builtin_amdgcn_s_sleep(1);
            }
            __syncthreads();
        }
    } else {
        // ------------------------- r block: 16 r-cols, tile 256+rb
        const int rb = bid - NGB;
        const f16* bh = Bph + (size_t)(256 + rb) * KSTEP * 512 + lane * 8;
        const f16* bl = Bpl + (size_t)(256 + rb) * KSTEP * 512 + lane * 8;
        const int rcol = rb * 16 + n;

        for (int t = 0; t < TT; ++t) {
            const int cur = t & 1, nxt = cur ^ 1;

            const f16* xh = x2h + ((size_t)t * BB + brow) * IC + quad * 8;
            const f16* xl = x2l + ((size_t)t * BB + brow) * IC + quad * 8;
            const f16* hh = hbh + (size_t)cur * BB * HC + (size_t)brow * HC + quad * 8;
            const f16* hl = hbl + (size_t)cur * BB * HC + (size_t)brow * HC + quad * 8;
            f32x4 acc[1] = {{0, 0, 0, 0}};
            gemm_tiles<1>(xh, xl, hh, hl, bh, bl, acc);

            if (rcol < DC) {
#pragma unroll
                for (int r = 0; r < 4; ++r) {
                    const int row = w * 16 + quad * 4 + r;
                    const float rv = fast_sigmoid(acc[0][r]);
                    const float dn = rv * dws[(size_t)cur * BB * DC + (size_t)row * DC + rcol];
                    dws[(size_t)nxt * BB * DC + (size_t)row * DC + rcol] = dn;
                    if (t == TT - 1)
                        out[(size_t)TT * BB * HC + 2 * BB * HC + (size_t)row * DC + rcol] = dn;
                }
            }

            // publish d_new: all waves drain, then release-signal
            __syncthreads();
            if (tid == 0)
                __hip_atomic_fetch_add(dcnt, 1u, __ATOMIC_RELEASE, __HIP_MEMORY_SCOPE_AGENT);

            // full barrier (wait for h publish)
            __syncthreads();
            if (tid == 0) {
                __hip_atomic_fetch_add(cnt, 1u, __ATOMIC_RELEASE, __HIP_MEMORY_SCOPE_AGENT);
                const unsigned tgt = (unsigned)NBLK * (t + 1);
                while (__hip_atomic_load(cnt, __ATOMIC_RELAXED, __HIP_MEMORY_SCOPE_AGENT) < tgt)
                    __builtin_amdgcn_s_sleep(1);
            }
            __syncthreads();
        }
    }
}

// ------------------------------------------------------------- launch

extern "C" void kernel_launch(void* const* d_in, const int* in_sizes, int n_in,
                              void* d_out, int out_size, void* d_ws, size_t ws_size,
                              hipStream_t stream) {
    const float* x   = (const float*)d_in[0];
    const float* h0  = (const float*)d_in[1];
    const float* c0  = (const float*)d_in[2];
    const float* d0  = (const float*)d_in[3];
    const float* Wx  = (const float*)d_in[4];
    const float* Wh  = (const float*)d_in[5];
    const float* bv  = (const float*)d_in[6];
    const float* Wrx = (const float*)d_in[7];
    const float* Wrh = (const float*)d_in[8];
    const float* Wd  = (const float*)d_in[9];
    float* out = (float*)d_out;

    char* ws = (char*)d_ws;
    unsigned* bar = (unsigned*)(ws + WS_BAR);
    f16*   x2h  = (f16*)(ws + WS_XH);
    f16*   x2l  = (f16*)(ws + WS_XL);
    f16*   Bph  = (f16*)(ws + WS_BPH);
    f16*   Bpl  = (f16*)(ws + WS_BPL);
    f16*   WdFh = (f16*)(ws + WS_WDFH);
    f16*   WdFl = (f16*)(ws + WS_WDFL);
    f16*   hbh  = (f16*)(ws + WS_HBH);
    f16*   hbl  = (f16*)(ws + WS_HBL);
    float* dws  = (float*)(ws + WS_DW);

    prep_x<<<TT * BB * IC / 4 / 256, 256, 0, stream>>>(x, x2h, x2l, TT * BB * IC);
    prep_B<<<NTILE * KSTEP, 64, 0, stream>>>(Wx, Wh, Wrx, Wrh, Bph, Bpl);
    prep_Wd<<<256, 64, 0, stream>>>(Wd, WdFh, WdFl);
    prep_misc<<<(BB * HC + 255) / 256, 256, 0, stream>>>(h0, hbh, hbl, d0, dws, bar);
    sclstm_main<<<NBLK, NTHR, 0, stream>>>(x2h, x2l, Bph, Bpl, WdFh, WdFl,
                                           hbh, hbl, dws, bv, c0, out, bar);
}

// Round 3
// 6378.802 us; speedup vs baseline: 2.8488x; 2.8488x over previous
//
#include <hip/hip_runtime.h>
#include <cstdint>

// ---------------------------------------------------------------------------
// SC-LSTM persistent kernel, MI355X (gfx950) — round 3.
//
//  * 256 blocks (1/CU), each owns 4 hidden cols (one 16-col MFMA gate tile).
//    Gate weights (hi+lo fp16 split) LDS-resident for all 256 steps (96 KB).
//  * Blocks 0..6 also own one reading-gate tile (B-hi fp16 only, 48 KB LDS)
//    computed on the SAME A-loads; they keep d-state in registers and
//    publish d in MFMA A-fragment order (producer-consumer dcnt counter).
//  * All cross-step operands (x, h, d) live in MFMA A-fragment layout:
//    frag[ks][lane][8] with k = ks*32 + (lane>>4)*8 + j, m = lane&15 —
//    every wave load is one contiguous 2 KB dwordx4 pair (hi+lo).
//  * h/d trajectories (257 slots, write-once addresses) -> consumers use
//    normal cached loads (L2-shared); producers publish via agent-scope 8B
//    write-through stores. Host falls back to 2-slot buffers + coalesced
//    bypass loads if ws_size is too small.
//  * One monotone grid barrier per step + one d-producer counter.
// ---------------------------------------------------------------------------

#define TT   256
#define BB   64
#define IC   512
#define HC   1024
#define DC   100
#define NG   4096
#define NRB  7
#define NBLK 256
#define NTHR 256

typedef _Float16 f16;
typedef f16   f16x8 __attribute__((ext_vector_type(8)));
typedef float f32x4 __attribute__((ext_vector_type(4)));
typedef unsigned long long u64;

// ---- workspace layout (bytes) ----
#define WS_BAR   0ull
#define WS_X     4096ull                       // x A-frags: 1048576 * 32 B
#define WS_WDF   (WS_X + 33554432ull)          // Wd B-frags: 16384 * 32 B
#define WS_D     (WS_WDF + 524288ull)          // d A-frag slots
#define D_SLOT   32768ull
#define H_SLOT   262144ull
#define WS_NEED_TRAJ (WS_D + 257ull * D_SLOT + 257ull * H_SLOT)   // ~104.8 MB

#define OFF_H  ((size_t)TT * BB * HC)
#define OFF_C  (OFF_H + (size_t)BB * HC)
#define OFF_D  (OFF_H + 2ull * BB * HC)

// ------------------------------------------------------------- helpers

__device__ __forceinline__ void split(float v, f16& hi, f16& lo) {
    hi = (f16)v;
    lo = (f16)(v - (float)hi);
}

__device__ __forceinline__ float fast_sigmoid(float x) {
    return 1.0f / (1.0f + __expf(-x));
}
__device__ __forceinline__ float fast_tanh(float x) {
    float ax = fabsf(x);
    float e  = __expf(-2.0f * ax);
    float r  = (1.0f - e) / (1.0f + e);
    return copysignf(r, x);
}

__device__ __forceinline__ void astore8(char* p, u64 v) {
    __hip_atomic_store((u64*)p, v, __ATOMIC_RELAXED, __HIP_MEMORY_SCOPE_AGENT);
}

// 32B A-frag load (hi 16B + lo 16B). TRAJ: normal cached. else: L2-bypass.
template <bool TRAJ>
__device__ __forceinline__ void loadAB(const char* p, f16x8& hi, f16x8& lo) {
    if constexpr (TRAJ) {
        hi = *(const f16x8*)p;
        lo = *(const f16x8*)(p + 16);
    } else {
        union { u64 q[2]; f16x8 v; } a, b;
        const u64* q = (const u64*)p;
        a.q[0] = __hip_atomic_load(q + 0, __ATOMIC_RELAXED, __HIP_MEMORY_SCOPE_AGENT);
        a.q[1] = __hip_atomic_load(q + 1, __ATOMIC_RELAXED, __HIP_MEMORY_SCOPE_AGENT);
        b.q[0] = __hip_atomic_load(q + 2, __ATOMIC_RELAXED, __HIP_MEMORY_SCOPE_AGENT);
        b.q[1] = __hip_atomic_load(q + 3, __ATOMIC_RELAXED, __HIP_MEMORY_SCOPE_AGENT);
        hi = a.v; lo = b.v;
    }
}

// ------------------------------------------------------------- prep kernels

__global__ void prep_x(const float* __restrict__ x, char* __restrict__ xF) {
    const int i = blockIdx.x * blockDim.x + threadIdx.x;   // < 1048576
    const int lane = i & 63, ks = (i >> 6) & 15, rg = (i >> 10) & 3, t = i >> 12;
    const int m = lane & 15, quad = lane >> 4;
    const float* src = x + (size_t)(t * BB + rg * 16 + m) * IC + ks * 32 + quad * 8;
    f16 hi[8], lo[8];
#pragma unroll
    for (int j = 0; j < 8; ++j) split(src[j], hi[j], lo[j]);
    char* dst = xF + (size_t)i * 32;
    *(f16x8*)dst        = *(f16x8*)hi;
    *(f16x8*)(dst + 16) = *(f16x8*)lo;
}

__global__ void prep_wdf(const float* __restrict__ Wd, char* __restrict__ WDF) {
    const int i = blockIdx.x * blockDim.x + threadIdx.x;   // < 16384
    const int lane = i & 63, kd = (i >> 6) & 3, s = i >> 8;
    const int n = lane & 15, quad = lane >> 4;
    f16 hi[8], lo[8];
#pragma unroll
    for (int j = 0; j < 8; ++j) {
        const int k = kd * 32 + quad * 8 + j;
        const float v = (k < DC) ? Wd[(size_t)k * HC + 16 * s + n] : 0.0f;
        split(v, hi[j], lo[j]);
    }
    char* dst = WDF + (size_t)i * 32;
    *(f16x8*)dst        = *(f16x8*)hi;
    *(f16x8*)(dst + 16) = *(f16x8*)lo;
}

__global__ void prep_h0(const float* __restrict__ h0, char* __restrict__ hT,
                        unsigned* __restrict__ bar) {
    const int i = blockIdx.x * blockDim.x + threadIdx.x;   // < 8192
    const int lane = i & 63, ks = (i >> 6) & 31, rg = i >> 11;
    const int m = lane & 15, quad = lane >> 4;
    const float* src = h0 + (size_t)(rg * 16 + m) * HC + ks * 32 + quad * 8;
    f16 hi[8], lo[8];
#pragma unroll
    for (int j = 0; j < 8; ++j) split(src[j], hi[j], lo[j]);
    char* dst = hT + (size_t)i * 32;
    *(f16x8*)dst        = *(f16x8*)hi;
    *(f16x8*)(dst + 16) = *(f16x8*)lo;
    if (i < 2) bar[i] = 0u;
}

__global__ void prep_d0(const float* __restrict__ d0, char* __restrict__ dT) {
    const int i = blockIdx.x * blockDim.x + threadIdx.x;   // < 1024
    const int lane = i & 63, kd = (i >> 6) & 3, rg = i >> 8;
    const int m = lane & 15, quad = lane >> 4;
    f16 hi[8], lo[8];
#pragma unroll
    for (int j = 0; j < 8; ++j) {
        const int k = kd * 32 + quad * 8 + j;
        const float v = (k < DC) ? d0[(size_t)(rg * 16 + m) * DC + k] : 0.0f;
        split(v, hi[j], lo[j]);
    }
    char* dst = dT + (size_t)i * 32;
    *(f16x8*)dst        = *(f16x8*)hi;
    *(f16x8*)(dst + 16) = *(f16x8*)lo;
}

// ------------------------------------------------------------- main kernel

template <bool TRAJ>
__global__ __launch_bounds__(NTHR) void sclstm_main(
    const char* __restrict__ xF, const char* __restrict__ WDF,
    char* hT, char* dT,
    const float* __restrict__ Wx, const float* __restrict__ Wh,
    const float* __restrict__ Wrx, const float* __restrict__ Wrh,
    const float* __restrict__ bvec, const float* __restrict__ c0,
    const float* __restrict__ d0, float* __restrict__ out,
    unsigned* bar) {

    const int g    = blockIdx.x;
    const int tid  = threadIdx.x;
    const int w    = tid >> 6;
    const int lane = tid & 63;
    const int n    = lane & 15;
    const int quad = lane >> 4;
    const bool withr = (g < NRB);

    // LDS map (155,904 B total)
    __shared__ __align__(16) char smem[155904];
    f16*  BFH = (f16*)(smem);                               // [48][64][8] gate B hi
    f16*  BFL = (f16*)(smem + 49152);                       // [48][64][8] gate B lo
    f16*  RBF = (f16*)(smem + 98304);                       // [48][64][8] r B hi
    float (*GL)[17]    = (float(*)[17])(smem + 147456);     // [64][17] gate preacts
    float (*TST)[16]   = (float(*)[16])(smem + 147456);     // fill stage (overlay GL)
    f16 (*DST)[32][16] = (f16(*)[32][16])(smem + 151808);   // [4][32][16] d stage
    float (*DAL)[5]    = (float(*)[5])(smem + 151808);      // [64][5] (overlay DST)
    f16 (*HST)[16][8]  = (f16(*)[16][8])(smem + 151808 + 1280); // [4][16][8] h stage

    unsigned* dcnt = bar;
    unsigned* cnt  = bar + 1;

    // ---------------- one-time: build gate B-frags in LDS from raw weights
    for (int ks = 0; ks < 48; ++ks) {
        if (tid < 128) {
            const int krow = tid >> 2, q = tid & 3;
            const int k = ks * 32 + krow;
            const float* W = (k < IC) ? (Wx + (size_t)k * NG)
                                      : (Wh + (size_t)(k - IC) * NG);
            const float4 v = *(const float4*)(W + q * HC + 4 * g);
            TST[krow][q * 4 + 0] = v.x; TST[krow][q * 4 + 1] = v.y;
            TST[krow][q * 4 + 2] = v.z; TST[krow][q * 4 + 3] = v.w;
        }
        __syncthreads();
#pragma unroll
        for (int e2 = 0; e2 < 2; ++e2) {
            const int e = tid * 2 + e2;
            const int le = e >> 3, j = e & 7;
            const float v = TST[(le >> 4) * 8 + j][le & 15];
            f16 hi, lo; split(v, hi, lo);
            BFH[(ks * 64 + le) * 8 + j] = hi;
            BFL[(ks * 64 + le) * 8 + j] = lo;
        }
        __syncthreads();
    }
    // one-time: r B-frags (hi only, alpha folded)
    if (withr) {
        for (int ks = 0; ks < 48; ++ks) {
            if (tid < 128) {
                const int krow = tid >> 2, cg = tid & 3;
                const int k = ks * 32 + krow;
                const int col0 = 16 * g + cg * 4;
                float4 v = make_float4(0.f, 0.f, 0.f, 0.f);
                if (col0 < DC) {
                    if (k < IC) v = *(const float4*)(Wrx + (size_t)k * DC + col0);
                    else {
                        float4 u = *(const float4*)(Wrh + (size_t)(k - IC) * DC + col0);
                        v = make_float4(0.5f * u.x, 0.5f * u.y, 0.5f * u.z, 0.5f * u.w);
                    }
                }
                TST[krow][cg * 4 + 0] = v.x; TST[krow][cg * 4 + 1] = v.y;
                TST[krow][cg * 4 + 2] = v.z; TST[krow][cg * 4 + 3] = v.w;
            }
            __syncthreads();
#pragma unroll
            for (int e2 = 0; e2 < 2; ++e2) {
                const int e = tid * 2 + e2;
                const int le = e >> 3, j = e & 7;
                RBF[(ks * 64 + le) * 8 + j] = (f16)TST[(le >> 4) * 8 + j][le & 15];
            }
            __syncthreads();
        }
    }

    // ---------------- per-thread state
    const float biasv = bvec[(n >> 2) * HC + g * 4 + (n & 3)];
    const int row2 = tid >> 2, jj = tid & 3;
    float c = c0[(size_t)row2 * HC + 4 * g + jj];
    float d_prev[4] = {0.f, 0.f, 0.f, 0.f};
    if (withr && 16 * g + n < DC) {
#pragma unroll
        for (int r = 0; r < 4; ++r)
            d_prev[r] = d0[(size_t)(w * 16 + quad * 4 + r) * DC + 16 * g + n];
    }
    __syncthreads();

    const int ksh = g >> 3, qkh = (g & 7) >> 1, jw = (g & 1) * 4;   // h-frag coords

    // ---------------- time loop
    for (int t = 0; t < TT; ++t) {
        const int slH  = TRAJ ? t : (t & 1);
        const int slH1 = TRAJ ? (t + 1) : ((t + 1) & 1);
        const int slD1 = slH1;

        // ---- phase 1: gate (+r) GEMM over K=1536, split precision ----
        f32x4 accg = {0.f, 0.f, 0.f, 0.f}, accr = {0.f, 0.f, 0.f, 0.f};
        {
            const char* xb = xF + (size_t)(t * 4 + w) * 32768;
            const char* hb = hT + (size_t)slH * H_SLOT + (size_t)w * 65536;
#pragma unroll
            for (int ks = 0; ks < 16; ++ks) {
                const char* ap = xb + (size_t)(ks * 64 + lane) * 32;
                f16x8 ah = *(const f16x8*)ap;
                f16x8 al = *(const f16x8*)(ap + 16);
                f16x8 bh = *(const f16x8*)(BFH + (ks * 64 + lane) * 8);
                f16x8 bl = *(const f16x8*)(BFL + (ks * 64 + lane) * 8);
                accg = __builtin_amdgcn_mfma_f32_16x16x32_f16(ah, bh, accg, 0, 0, 0);
                accg = __builtin_amdgcn_mfma_f32_16x16x32_f16(ah, bl, accg, 0, 0, 0);
                accg = __builtin_amdgcn_mfma_f32_16x16x32_f16(al, bh, accg, 0, 0, 0);
                if (withr) {
                    f16x8 rb = *(const f16x8*)(RBF + (ks * 64 + lane) * 8);
                    accr = __builtin_amdgcn_mfma_f32_16x16x32_f16(ah, rb, accr, 0, 0, 0);
                    accr = __builtin_amdgcn_mfma_f32_16x16x32_f16(al, rb, accr, 0, 0, 0);
                }
            }
#pragma unroll
            for (int ks = 16; ks < 48; ++ks) {
                f16x8 ah, al;
                loadAB<TRAJ>(hb + (size_t)((ks - 16) * 64 + lane) * 32, ah, al);
                f16x8 bh = *(const f16x8*)(BFH + (ks * 64 + lane) * 8);
                f16x8 bl = *(const f16x8*)(BFL + (ks * 64 + lane) * 8);
                accg = __builtin_amdgcn_mfma_f32_16x16x32_f16(ah, bh, accg, 0, 0, 0);
                accg = __builtin_amdgcn_mfma_f32_16x16x32_f16(ah, bl, accg, 0, 0, 0);
                accg = __builtin_amdgcn_mfma_f32_16x16x32_f16(al, bh, accg, 0, 0, 0);
                if (withr) {
                    f16x8 rb = *(const f16x8*)(RBF + (ks * 64 + lane) * 8);
                    accr = __builtin_amdgcn_mfma_f32_16x16x32_f16(ah, rb, accr, 0, 0, 0);
                    accr = __builtin_amdgcn_mfma_f32_16x16x32_f16(al, rb, accr, 0, 0, 0);
                }
            }
        }

        // ---- phase 2: gate preacts -> LDS (C/D: col=n, row=quad*4+r) ----
#pragma unroll
        for (int r = 0; r < 4; ++r)
            GL[w * 16 + quad * 4 + r][n] = accg[r] + biasv;

        // ---- phase 3 (blocks 0..6): d update + publish ----
        if (withr) {
#pragma unroll
            for (int r = 0; r < 4; ++r) {
                const float rv = fast_sigmoid(accr[r]);
                const float dn = rv * d_prev[r];
                d_prev[r] = dn;
                f16 hi, lo; split(dn, hi, lo);
                const int sr = (n >> 3) * 16 + quad * 4 + r;
                DST[w][sr][n & 7]       = hi;
                DST[w][sr][8 + (n & 7)] = lo;
            }
            if (t == TT - 1 && 16 * g + n < DC) {
#pragma unroll
                for (int r = 0; r < 4; ++r)
                    out[OFF_D + (size_t)(w * 16 + quad * 4 + r) * DC + 16 * g + n] = d_prev[r];
            }
            __syncthreads();
            {
                const int rg = tid >> 6, l32 = (tid >> 1) & 31, part = tid & 1;
                char* base = dT + (size_t)slD1 * D_SLOT;
                char* dp = base + (size_t)((rg * 4 + (g >> 1)) * 64 + 32 * (g & 1) + l32) * 32
                           + part * 8;
                astore8(dp,      *(const u64*)&DST[rg][l32][part * 4]);
                astore8(dp + 16, *(const u64*)&DST[rg][l32][8 + part * 4]);
                if (g == 6) {   // zero-fill d-frag cols 112..127 (ksd=3, lanes 32..63)
                    char* zp = base + (size_t)((rg * 4 + 3) * 64 + 32 + l32) * 32 + part * 8;
                    astore8(zp, 0ull); astore8(zp + 16, 0ull);
                }
            }
            __syncthreads();   // drain d stores (per-wave vmcnt) before signal
            if (tid == 0)
                __hip_atomic_fetch_add(dcnt, 1u, __ATOMIC_RELEASE, __HIP_MEMORY_SCOPE_AGENT);
        }

        // ---- phase 4: wait for all 7 d producers ----
        if (tid == 0) {
            const unsigned tgt = (unsigned)NRB * (t + 1);
            while (__hip_atomic_load(dcnt, __ATOMIC_RELAXED, __HIP_MEMORY_SCOPE_AGENT) < tgt)
                __builtin_amdgcn_s_sleep(1);
        }
        __syncthreads();

        // ---- phase 5: da = d_new @ Wd (K=128, split precision) ----
        {
            f32x4 da = {0.f, 0.f, 0.f, 0.f};
            const char* db = dT + (size_t)slD1 * D_SLOT + (size_t)w * 8192;
            const char* wb = WDF + (size_t)(g >> 2) * 8192;
#pragma unroll
            for (int kd = 0; kd < 4; ++kd) {
                f16x8 dh, dl;
                loadAB<TRAJ>(db + (size_t)(kd * 64 + lane) * 32, dh, dl);
                const char* wp = wb + (size_t)(kd * 64 + lane) * 32;
                f16x8 wh = *(const f16x8*)wp;
                f16x8 wl = *(const f16x8*)(wp + 16);
                da = __builtin_amdgcn_mfma_f32_16x16x32_f16(dh, wh, da, 0, 0, 0);
                da = __builtin_amdgcn_mfma_f32_16x16x32_f16(dh, wl, da, 0, 0, 0);
                da = __builtin_amdgcn_mfma_f32_16x16x32_f16(dl, wh, da, 0, 0, 0);
            }
            const int wo = n - 4 * (g & 3);
            if ((unsigned)wo < 4u) {
#pragma unroll
                for (int r = 0; r < 4; ++r)
                    DAL[w * 16 + quad * 4 + r][wo] = da[r];
            }
        }
        __syncthreads();

        // ---- phase 6: c/h update (1 state/thread) ----
        {
            const float iv = fast_sigmoid(GL[row2][jj]);
            const float fv = fast_sigmoid(GL[row2][4 + jj]);
            const float gv = fast_tanh(GL[row2][8 + jj]);
            const float ov = fast_sigmoid(GL[row2][12 + jj]);
            c = fv * c + iv * gv + fast_tanh(DAL[row2][jj]);
            const float h = ov * fast_tanh(c);
            out[((size_t)t * BB + row2) * HC + 4 * g + jj] = h;
            f16 hh_, hl_; split(h, hh_, hl_);
            HST[row2 >> 4][row2 & 15][jj]     = hh_;
            HST[row2 >> 4][row2 & 15][4 + jj] = hl_;
            if (t == TT - 1) {
                out[OFF_H + (size_t)row2 * HC + 4 * g + jj] = h;
                out[OFF_C + (size_t)row2 * HC + 4 * g + jj] = c;
            }
        }
        __syncthreads();

        // ---- phase 7: publish h fragment (coalesced 8B sc1 stores) ----
        if (tid < 128) {
            const int rg = tid >> 5, m = (tid >> 1) & 15, half = tid & 1;
            const u64 v = *(const u64*)&HST[rg][m][half * 4];
            char* p = hT + (size_t)slH1 * H_SLOT
                      + (size_t)((rg * 32 + ksh) * 64 + qkh * 16 + m) * 32
                      + half * 16 + jw * 2;
            astore8(p, v);
        }
        __syncthreads();   // drain h stores before barrier signal

        // ---- phase 8: grid barrier (monotone) ----
        if (tid == 0) {
            __hip_atomic_fetch_add(cnt, 1u, __ATOMIC_RELEASE, __HIP_MEMORY_SCOPE_AGENT);
            const unsigned tgt = (unsigned)NBLK * (t + 1);
            while (__hip_atomic_load(cnt, __ATOMIC_RELAXED, __HIP_MEMORY_SCOPE_AGENT) < tgt)
                __builtin_amdgcn_s_sleep(2);
        }
        __syncthreads();
    }
}

// ------------------------------------------------------------- launch

extern "C" void kernel_launch(void* const* d_in, const int* in_sizes, int n_in,
                              void* d_out, int out_size, void* d_ws, size_t ws_size,
                              hipStream_t stream) {
    const float* x   = (const float*)d_in[0];
    const float* h0  = (const float*)d_in[1];
    const float* c0  = (const float*)d_in[2];
    const float* d0  = (const float*)d_in[3];
    const float* Wx  = (const float*)d_in[4];
    const float* Wh  = (const float*)d_in[5];
    const float* bv  = (const float*)d_in[6];
    const float* Wrx = (const float*)d_in[7];
    const float* Wrh = (const float*)d_in[8];
    const float* Wd  = (const float*)d_in[9];
    float* out = (float*)d_out;

    char* ws = (char*)d_ws;
    const bool traj = (ws_size >= (size_t)WS_NEED_TRAJ);
    const int dslots = traj ? 257 : 2;

    unsigned* bar = (unsigned*)(ws + WS_BAR);
    char* xF  = ws + WS_X;
    char* WDF = ws + WS_WDF;
    char* dT  = ws + WS_D;
    char* hT  = dT + (size_t)dslots * D_SLOT;

    prep_x<<<4096, 256, 0, stream>>>(x, xF);
    prep_wdf<<<64, 256, 0, stream>>>(Wd, WDF);
    prep_h0<<<32, 256, 0, stream>>>(h0, hT, bar);
    prep_d0<<<4, 256, 0, stream>>>(d0, dT);

    if (traj)
        sclstm_main<true><<<NBLK, NTHR, 0, stream>>>(xF, WDF, hT, dT, Wx, Wh, Wrx, Wrh,
                                                     bv, c0, d0, out, bar);
    else
        sclstm_main<false><<<NBLK, NTHR, 0, stream>>>(xF, WDF, hT, dT, Wx, Wh, Wrx, Wrh,
                                                      bv, c0, d0, out, bar);
}

// Round 4
// 4709.381 us; speedup vs baseline: 3.8587x; 1.3545x over previous
//
#include <hip/hip_runtime.h>
#include <cstdint>

// ---------------------------------------------------------------------------
// SC-LSTM persistent kernel, MI355X (gfx950) — round 4.
//
//  vs round 3 (6.38 ms, 24.9 us/step with ~4 us of real work):
//  * Hierarchical grid barrier: 8 group counters -> root -> 8 broadcast
//    epoch mirrors; blocks poll only their group mirror (written once/step).
//    Kills the 256-poller/256-RMW single-LLC-line hotspot (was ~20 us/step).
//  * 512 threads/block (8 waves = 2/SIMD): split-K GEMM (waves 0-3: ks 0..23,
//    waves 4-7: ks 24..47), partials reduced via 4 KB LDS. 2x TLP + half the
//    per-wave load chain.
//  * 3 independent MFMA accumulators (hh/hl/lh) — issue at throughput (~5cy)
//    instead of single-acc dependency latency (~17cy).
//  Everything else identical to round 3 (split-precision fp16, LDS-resident
//  weights, MFMA-fragment-layout trajectories for x/h/d, write-once slots).
// ---------------------------------------------------------------------------

#define TT   256
#define BB   64
#define IC   512
#define HC   1024
#define DC   100
#define NG   4096
#define NRB  7
#define NBLK 256
#define NTHR 512

typedef _Float16 f16;
typedef f16   f16x8 __attribute__((ext_vector_type(8)));
typedef float f32x4 __attribute__((ext_vector_type(4)));
typedef unsigned long long u64;

// ---- workspace layout (bytes) ----
#define WS_BAR   0ull                          // 8192 B of counters/mirrors
#define WS_X     8192ull                       // x A-frags: 1048576 * 32 B
#define WS_WDF   (WS_X + 33554432ull)          // Wd B-frags: 16384 * 32 B
#define WS_D     (WS_WDF + 524288ull)          // d A-frag slots
#define D_SLOT   32768ull
#define H_SLOT   262144ull
#define WS_NEED_TRAJ (WS_D + 257ull * D_SLOT + 257ull * H_SLOT)

// barrier word indices (spaced 64 uints = 256 B, all separate lines)
#define BAR_GRP(g)   (64 * (g))          // 8 group arrival counters
#define BAR_ROOT     512                 // root arrival counter
#define BAR_EPOCH(g) (576 + 64 * (g))    // 8 epoch mirrors
#define BAR_DCNT     1088                // d-producer counter
#define BAR_DEP(g)   (1152 + 64 * (g))   // 8 depoch mirrors

#define OFF_H  ((size_t)TT * BB * HC)
#define OFF_C  (OFF_H + (size_t)BB * HC)
#define OFF_D  (OFF_H + 2ull * BB * HC)

// ------------------------------------------------------------- helpers

__device__ __forceinline__ void split(float v, f16& hi, f16& lo) {
    hi = (f16)v;
    lo = (f16)(v - (float)hi);
}

__device__ __forceinline__ float fast_sigmoid(float x) {
    return 1.0f / (1.0f + __expf(-x));
}
__device__ __forceinline__ float fast_tanh(float x) {
    float ax = fabsf(x);
    float e  = __expf(-2.0f * ax);
    float r  = (1.0f - e) / (1.0f + e);
    return copysignf(r, x);
}

__device__ __forceinline__ void astore8(char* p, u64 v) {
    __hip_atomic_store((u64*)p, v, __ATOMIC_RELAXED, __HIP_MEMORY_SCOPE_AGENT);
}
__device__ __forceinline__ void astore4(unsigned* p, unsigned v) {
    __hip_atomic_store(p, v, __ATOMIC_RELEASE, __HIP_MEMORY_SCOPE_AGENT);
}
__device__ __forceinline__ unsigned aload4(const unsigned* p) {
    return __hip_atomic_load(p, __ATOMIC_RELAXED, __HIP_MEMORY_SCOPE_AGENT);
}

// 32B A-frag load (hi 16B + lo 16B). TRAJ: normal cached. else: L2-bypass.
template <bool TRAJ>
__device__ __forceinline__ void loadAB(const char* p, f16x8& hi, f16x8& lo) {
    if constexpr (TRAJ) {
        hi = *(const f16x8*)p;
        lo = *(const f16x8*)(p + 16);
    } else {
        union { u64 q[2]; f16x8 v; } a, b;
        const u64* q = (const u64*)p;
        a.q[0] = __hip_atomic_load(q + 0, __ATOMIC_RELAXED, __HIP_MEMORY_SCOPE_AGENT);
        a.q[1] = __hip_atomic_load(q + 1, __ATOMIC_RELAXED, __HIP_MEMORY_SCOPE_AGENT);
        b.q[0] = __hip_atomic_load(q + 2, __ATOMIC_RELAXED, __HIP_MEMORY_SCOPE_AGENT);
        b.q[1] = __hip_atomic_load(q + 3, __ATOMIC_RELAXED, __HIP_MEMORY_SCOPE_AGENT);
        hi = a.v; lo = b.v;
    }
}

// ------------------------------------------------------------- prep kernels

__global__ void prep_x(const float* __restrict__ x, char* __restrict__ xF) {
    const int i = blockIdx.x * blockDim.x + threadIdx.x;   // < 1048576
    const int lane = i & 63, ks = (i >> 6) & 15, rg = (i >> 10) & 3, t = i >> 12;
    const int m = lane & 15, quad = lane >> 4;
    const float* src = x + (size_t)(t * BB + rg * 16 + m) * IC + ks * 32 + quad * 8;
    f16 hi[8], lo[8];
#pragma unroll
    for (int j = 0; j < 8; ++j) split(src[j], hi[j], lo[j]);
    char* dst = xF + (size_t)i * 32;
    *(f16x8*)dst        = *(f16x8*)hi;
    *(f16x8*)(dst + 16) = *(f16x8*)lo;
}

__global__ void prep_wdf(const float* __restrict__ Wd, char* __restrict__ WDF) {
    const int i = blockIdx.x * blockDim.x + threadIdx.x;   // < 16384
    const int lane = i & 63, kd = (i >> 6) & 3, s = i >> 8;
    const int n = lane & 15, quad = lane >> 4;
    f16 hi[8], lo[8];
#pragma unroll
    for (int j = 0; j < 8; ++j) {
        const int k = kd * 32 + quad * 8 + j;
        const float v = (k < DC) ? Wd[(size_t)k * HC + 16 * s + n] : 0.0f;
        split(v, hi[j], lo[j]);
    }
    char* dst = WDF + (size_t)i * 32;
    *(f16x8*)dst        = *(f16x8*)hi;
    *(f16x8*)(dst + 16) = *(f16x8*)lo;
}

__global__ void prep_h0(const float* __restrict__ h0, char* __restrict__ hT,
                        unsigned* __restrict__ bar) {
    const int i = blockIdx.x * blockDim.x + threadIdx.x;   // < 8192
    const int lane = i & 63, ks = (i >> 6) & 31, rg = i >> 11;
    const int m = lane & 15, quad = lane >> 4;
    const float* src = h0 + (size_t)(rg * 16 + m) * HC + ks * 32 + quad * 8;
    f16 hi[8], lo[8];
#pragma unroll
    for (int j = 0; j < 8; ++j) split(src[j], hi[j], lo[j]);
    char* dst = hT + (size_t)i * 32;
    *(f16x8*)dst        = *(f16x8*)hi;
    *(f16x8*)(dst + 16) = *(f16x8*)lo;
    if (i < 2048) bar[i] = 0u;
}

__global__ void prep_d0(const float* __restrict__ d0, char* __restrict__ dT) {
    const int i = blockIdx.x * blockDim.x + threadIdx.x;   // < 1024
    const int lane = i & 63, kd = (i >> 6) & 3, rg = i >> 8;
    const int m = lane & 15, quad = lane >> 4;
    f16 hi[8], lo[8];
#pragma unroll
    for (int j = 0; j < 8; ++j) {
        const int k = kd * 32 + quad * 8 + j;
        const float v = (k < DC) ? d0[(size_t)(rg * 16 + m) * DC + k] : 0.0f;
        split(v, hi[j], lo[j]);
    }
    char* dst = dT + (size_t)i * 32;
    *(f16x8*)dst        = *(f16x8*)hi;
    *(f16x8*)(dst + 16) = *(f16x8*)lo;
}

// ------------------------------------------------------------- main kernel

template <bool TRAJ>
__global__ __launch_bounds__(NTHR) void sclstm_main(
    const char* __restrict__ xF, const char* __restrict__ WDF,
    char* hT, char* dT,
    const float* __restrict__ Wx, const float* __restrict__ Wh,
    const float* __restrict__ Wrx, const float* __restrict__ Wrh,
    const float* __restrict__ bvec, const float* __restrict__ c0,
    const float* __restrict__ d0, float* __restrict__ out,
    unsigned* bar) {

    const int g    = blockIdx.x;
    const int grp  = g & 7;                 // barrier group (XCD-aligned heuristic)
    const int tid  = threadIdx.x;
    const int w    = tid >> 6;
    const int half = w >> 2;                // 0: ks 0..23, 1: ks 24..47
    const int wrow = w & 3;                 // 16-row A tile
    const int lane = tid & 63;
    const int n    = lane & 15;
    const int quad = lane >> 4;
    const bool withr = (g < NRB);

    // LDS map (155,904 B total)
    __shared__ __align__(16) char smem[155904];
    f16*  BFH = (f16*)(smem);                               // [48][64][8] gate B hi
    f16*  BFL = (f16*)(smem + 49152);                       // [48][64][8] gate B lo
    f16*  RBF = (f16*)(smem + 98304);                       // [48][64][8] r B hi
    float (*GL)[17]    = (float(*)[17])(smem + 147456);     // [64][17] gate preacts
    float (*TST)[16]   = (float(*)[16])(smem + 147456);     // stage (overlay GL)
    f32x4* PART        = (f32x4*)(smem + 151808);           // [4][64] split-K partials
    f16 (*DST)[32][16] = (f16(*)[32][16])(smem + 151808);   // [4][32][16] d stage
    float (*DAL)[5]    = (float(*)[5])(smem + 151808);      // [64][5] (overlay DST)
    f16 (*HST)[16][8]  = (f16(*)[16][8])(smem + 151808 + 1280); // [4][16][8] h stage

    // ---------------- one-time: gate B-frags in LDS (2 ks rows per iter)
    for (int ks2 = 0; ks2 < 24; ++ks2) {
        if (tid < 256) {
            const int krow = tid >> 2, q = tid & 3;
            const int k = ks2 * 64 + krow;
            const float* W = (k < IC) ? (Wx + (size_t)k * NG)
                                      : (Wh + (size_t)(k - IC) * NG);
            const float4 v = *(const float4*)(W + q * HC + 4 * g);
            TST[krow][q * 4 + 0] = v.x; TST[krow][q * 4 + 1] = v.y;
            TST[krow][q * 4 + 2] = v.z; TST[krow][q * 4 + 3] = v.w;
        }
        __syncthreads();
#pragma unroll
        for (int e2 = 0; e2 < 2; ++e2) {
            const int e = tid * 2 + e2;             // 0..1023
            const int ksl = e >> 9, le = (e >> 3) & 63, j = e & 7;
            const float v = TST[ksl * 32 + (le >> 4) * 8 + j][le & 15];
            f16 hi, lo; split(v, hi, lo);
            const int ks = ks2 * 2 + ksl;
            BFH[(ks * 64 + le) * 8 + j] = hi;
            BFL[(ks * 64 + le) * 8 + j] = lo;
        }
        __syncthreads();
    }
    // one-time: r B-frags (hi only, alpha folded)
    if (withr) {
        for (int ks2 = 0; ks2 < 24; ++ks2) {
            if (tid < 256) {
                const int krow = tid >> 2, cg = tid & 3;
                const int k = ks2 * 64 + krow;
                const int col0 = 16 * g + cg * 4;
                float4 v = make_float4(0.f, 0.f, 0.f, 0.f);
                if (col0 < DC) {
                    if (k < IC) v = *(const float4*)(Wrx + (size_t)k * DC + col0);
                    else {
                        float4 u = *(const float4*)(Wrh + (size_t)(k - IC) * DC + col0);
                        v = make_float4(0.5f * u.x, 0.5f * u.y, 0.5f * u.z, 0.5f * u.w);
                    }
                }
                TST[krow][cg * 4 + 0] = v.x; TST[krow][cg * 4 + 1] = v.y;
                TST[krow][cg * 4 + 2] = v.z; TST[krow][cg * 4 + 3] = v.w;
            }
            __syncthreads();
#pragma unroll
            for (int e2 = 0; e2 < 2; ++e2) {
                const int e = tid * 2 + e2;
                const int ksl = e >> 9, le = (e >> 3) & 63, j = e & 7;
                const int ks = ks2 * 2 + ksl;
                RBF[(ks * 64 + le) * 8 + j] = (f16)TST[ksl * 32 + (le >> 4) * 8 + j][le & 15];
            }
            __syncthreads();
        }
    }

    // ---------------- per-thread state
    const float biasv = bvec[(n >> 2) * HC + g * 4 + (n & 3)];
    const int row2 = tid >> 2, jj = tid & 3;        // valid for tid < 256
    float c = 0.f;
    if (tid < 256) c = c0[(size_t)row2 * HC + 4 * g + jj];
    float d_prev[4] = {0.f, 0.f, 0.f, 0.f};
    if (withr && half == 0 && 16 * g + n < DC) {
#pragma unroll
        for (int r = 0; r < 4; ++r)
            d_prev[r] = d0[(size_t)(wrow * 16 + quad * 4 + r) * DC + 16 * g + n];
    }
    __syncthreads();

    const int ksh = g >> 3, qkh = (g & 7) >> 1, jw = (g & 1) * 4;   // h-frag coords

    // ---------------- time loop
    for (int t = 0; t < TT; ++t) {
        const int slH  = TRAJ ? t : (t & 1);
        const int slH1 = TRAJ ? (t + 1) : ((t + 1) & 1);
        const int slD1 = slH1;

        // ---- phase 1: split-K gate (+r) GEMM, 3 independent accumulators ----
        f32x4 ghh = {0,0,0,0}, ghl = {0,0,0,0}, glh = {0,0,0,0};
        f32x4 rh = {0,0,0,0}, rl = {0,0,0,0};
        {
            const char* xb = xF + (size_t)(t * 4 + wrow) * 32768;
            const char* hb = hT + (size_t)slH * H_SLOT + (size_t)wrow * 65536;
            if (half == 0) {
#pragma unroll
                for (int ks = 0; ks < 16; ++ks) {      // x part
                    const char* ap = xb + (size_t)(ks * 64 + lane) * 32;
                    f16x8 ah = *(const f16x8*)ap;
                    f16x8 al = *(const f16x8*)(ap + 16);
                    f16x8 bh = *(const f16x8*)(BFH + (ks * 64 + lane) * 8);
                    f16x8 bl = *(const f16x8*)(BFL + (ks * 64 + lane) * 8);
                    ghh = __builtin_amdgcn_mfma_f32_16x16x32_f16(ah, bh, ghh, 0, 0, 0);
                    ghl = __builtin_amdgcn_mfma_f32_16x16x32_f16(ah, bl, ghl, 0, 0, 0);
                    glh = __builtin_amdgcn_mfma_f32_16x16x32_f16(al, bh, glh, 0, 0, 0);
                    if (withr) {
                        f16x8 rb = *(const f16x8*)(RBF + (ks * 64 + lane) * 8);
                        rh = __builtin_amdgcn_mfma_f32_16x16x32_f16(ah, rb, rh, 0, 0, 0);
                        rl = __builtin_amdgcn_mfma_f32_16x16x32_f16(al, rb, rl, 0, 0, 0);
                    }
                }
#pragma unroll
                for (int ks = 16; ks < 24; ++ks) {     // h part (first chunk)
                    f16x8 ah, al;
                    loadAB<TRAJ>(hb + (size_t)((ks - 16) * 64 + lane) * 32, ah, al);
                    f16x8 bh = *(const f16x8*)(BFH + (ks * 64 + lane) * 8);
                    f16x8 bl = *(const f16x8*)(BFL + (ks * 64 + lane) * 8);
                    ghh = __builtin_amdgcn_mfma_f32_16x16x32_f16(ah, bh, ghh, 0, 0, 0);
                    ghl = __builtin_amdgcn_mfma_f32_16x16x32_f16(ah, bl, ghl, 0, 0, 0);
                    glh = __builtin_amdgcn_mfma_f32_16x16x32_f16(al, bh, glh, 0, 0, 0);
                    if (withr) {
                        f16x8 rb = *(const f16x8*)(RBF + (ks * 64 + lane) * 8);
                        rh = __builtin_amdgcn_mfma_f32_16x16x32_f16(ah, rb, rh, 0, 0, 0);
                        rl = __builtin_amdgcn_mfma_f32_16x16x32_f16(al, rb, rl, 0, 0, 0);
                    }
                }
            } else {
#pragma unroll
                for (int ks = 24; ks < 48; ++ks) {     // h part (second chunk)
                    f16x8 ah, al;
                    loadAB<TRAJ>(hb + (size_t)((ks - 16) * 64 + lane) * 32, ah, al);
                    f16x8 bh = *(const f16x8*)(BFH + (ks * 64 + lane) * 8);
                    f16x8 bl = *(const f16x8*)(BFL + (ks * 64 + lane) * 8);
                    ghh = __builtin_amdgcn_mfma_f32_16x16x32_f16(ah, bh, ghh, 0, 0, 0);
                    ghl = __builtin_amdgcn_mfma_f32_16x16x32_f16(ah, bl, ghl, 0, 0, 0);
                    glh = __builtin_amdgcn_mfma_f32_16x16x32_f16(al, bh, glh, 0, 0, 0);
                    if (withr) {
                        f16x8 rb = *(const f16x8*)(RBF + (ks * 64 + lane) * 8);
                        rh = __builtin_amdgcn_mfma_f32_16x16x32_f16(ah, rb, rh, 0, 0, 0);
                        rl = __builtin_amdgcn_mfma_f32_16x16x32_f16(al, rb, rl, 0, 0, 0);
                    }
                }
            }
        }
        f32x4 accg = ghh + ghl + glh;
        f32x4 accr = rh + rl;

        // ---- split-K reduction (gate) ----
        if (half == 1) PART[wrow * 64 + lane] = accg;
        __syncthreads();
        if (half == 0) accg += PART[wrow * 64 + lane];
        // ---- split-K reduction (r, r-blocks only) ----
        if (withr) {
            __syncthreads();
            if (half == 1) PART[wrow * 64 + lane] = accr;
            __syncthreads();
            if (half == 0) accr += PART[wrow * 64 + lane];
        }

        // ---- phase 2: gate preacts -> LDS (C/D: col=n, row=quad*4+r) ----
        if (half == 0) {
#pragma unroll
            for (int r = 0; r < 4; ++r)
                GL[wrow * 16 + quad * 4 + r][n] = accg[r] + biasv;
        }

        // ---- phase 3 (blocks 0..6): d update + publish ----
        if (withr) {
            if (half == 0) {
#pragma unroll
                for (int r = 0; r < 4; ++r) {
                    const float rv = fast_sigmoid(accr[r]);
                    const float dn = rv * d_prev[r];
                    d_prev[r] = dn;
                    f16 hi, lo; split(dn, hi, lo);
                    const int sr = (n >> 3) * 16 + quad * 4 + r;
                    DST[wrow][sr][n & 7]       = hi;
                    DST[wrow][sr][8 + (n & 7)] = lo;
                }
                if (t == TT - 1 && 16 * g + n < DC) {
#pragma unroll
                    for (int r = 0; r < 4; ++r)
                        out[OFF_D + (size_t)(wrow * 16 + quad * 4 + r) * DC + 16 * g + n] = d_prev[r];
                }
            }
            __syncthreads();
            if (tid < 256) {
                const int rg = tid >> 6, l32 = (tid >> 1) & 31, part = tid & 1;
                char* base = dT + (size_t)slD1 * D_SLOT;
                char* dp = base + (size_t)((rg * 4 + (g >> 1)) * 64 + 32 * (g & 1) + l32) * 32
                           + part * 8;
                astore8(dp,      *(const u64*)&DST[rg][l32][part * 4]);
                astore8(dp + 16, *(const u64*)&DST[rg][l32][8 + part * 4]);
                if (g == 6) {   // zero-fill d-frag cols 112..127
                    char* zp = base + (size_t)((rg * 4 + 3) * 64 + 32 + l32) * 32 + part * 8;
                    astore8(zp, 0ull); astore8(zp + 16, 0ull);
                }
            }
            __syncthreads();   // drain d stores before signal
            if (tid == 0) {
                unsigned o = __hip_atomic_fetch_add(bar + BAR_DCNT, 1u,
                                 __ATOMIC_RELEASE, __HIP_MEMORY_SCOPE_AGENT);
                if (o % NRB == NRB - 1) {   // last d producer this step
#pragma unroll
                    for (int e = 0; e < 8; ++e) astore4(bar + BAR_DEP(e), t + 1);
                }
            }
        }

        // ---- phase 4: wait for d-ready broadcast ----
        if (tid == 0) {
            while (aload4(bar + BAR_DEP(grp)) < (unsigned)(t + 1))
                __builtin_amdgcn_s_sleep(1);
        }
        __syncthreads();

        // ---- phase 5: da = d_new @ Wd (K=128, split precision) ----
        if (half == 0) {
            f32x4 da = {0,0,0,0};
            const char* db = dT + (size_t)slD1 * D_SLOT + (size_t)wrow * 8192;
            const char* wb = WDF + (size_t)(g >> 2) * 8192;
#pragma unroll
            for (int kd = 0; kd < 4; ++kd) {
                f16x8 dh, dl;
                loadAB<TRAJ>(db + (size_t)(kd * 64 + lane) * 32, dh, dl);
                const char* wp = wb + (size_t)(kd * 64 + lane) * 32;
                f16x8 wh = *(const f16x8*)wp;
                f16x8 wl = *(const f16x8*)(wp + 16);
                da = __builtin_amdgcn_mfma_f32_16x16x32_f16(dh, wh, da, 0, 0, 0);
                da = __builtin_amdgcn_mfma_f32_16x16x32_f16(dh, wl, da, 0, 0, 0);
                da = __builtin_amdgcn_mfma_f32_16x16x32_f16(dl, wh, da, 0, 0, 0);
            }
            const int wo = n - 4 * (g & 3);
            if ((unsigned)wo < 4u) {
#pragma unroll
                for (int r = 0; r < 4; ++r)
                    DAL[wrow * 16 + quad * 4 + r][wo] = da[r];
            }
        }
        __syncthreads();

        // ---- phase 6: c/h update (1 state/thread, threads 0..255) ----
        if (tid < 256) {
            const float iv = fast_sigmoid(GL[row2][jj]);
            const float fv = fast_sigmoid(GL[row2][4 + jj]);
            const float gv = fast_tanh(GL[row2][8 + jj]);
            const float ov = fast_sigmoid(GL[row2][12 + jj]);
            c = fv * c + iv * gv + fast_tanh(DAL[row2][jj]);
            const float h = ov * fast_tanh(c);
            out[((size_t)t * BB + row2) * HC + 4 * g + jj] = h;
            f16 hh_, hl_; split(h, hh_, hl_);
            HST[row2 >> 4][row2 & 15][jj]     = hh_;
            HST[row2 >> 4][row2 & 15][4 + jj] = hl_;
            if (t == TT - 1) {
                out[OFF_H + (size_t)row2 * HC + 4 * g + jj] = h;
                out[OFF_C + (size_t)row2 * HC + 4 * g + jj] = c;
            }
        }
        __syncthreads();

        // ---- phase 7: publish h fragment (coalesced 8B stores) ----
        if (tid < 128) {
            const int rg = tid >> 5, m = (tid >> 1) & 15, hlf = tid & 1;
            const u64 v = *(const u64*)&HST[rg][m][hlf * 4];
            char* p = hT + (size_t)slH1 * H_SLOT
                      + (size_t)((rg * 32 + ksh) * 64 + qkh * 16 + m) * 32
                      + hlf * 16 + jw * 2;
            astore8(p, v);
        }
        __syncthreads();   // drain h stores before arrival

        // ---- phase 8: hierarchical grid barrier ----
        if (tid == 0) {
            unsigned o = __hip_atomic_fetch_add(bar + BAR_GRP(grp), 1u,
                             __ATOMIC_RELEASE, __HIP_MEMORY_SCOPE_AGENT);
            if ((o & 31) == 31) {           // last in group
                unsigned o2 = __hip_atomic_fetch_add(bar + BAR_ROOT, 1u,
                                  __ATOMIC_RELEASE, __HIP_MEMORY_SCOPE_AGENT);
                if ((o2 & 7) == 7) {        // last overall: broadcast epoch
#pragma unroll
                    for (int e = 0; e < 8; ++e) astore4(bar + BAR_EPOCH(e), t + 1);
                }
            }
            while (aload4(bar + BAR_EPOCH(grp)) < (unsigned)(t + 1))
                __builtin_amdgcn_s_sleep(2);
        }
        __syncthreads();
    }
}

// ------------------------------------------------------------- launch

extern "C" void kernel_launch(void* const* d_in, const int* in_sizes, int n_in,
                              void* d_out, int out_size, void* d_ws, size_t ws_size,
                              hipStream_t stream) {
    const float* x   = (const float*)d_in[0];
    const float* h0  = (const float*)d_in[1];
    const float* c0  = (const float*)d_in[2];
    const float* d0  = (const float*)d_in[3];
    const float* Wx  = (const float*)d_in[4];
    const float* Wh  = (const float*)d_in[5];
    const float* bv  = (const float*)d_in[6];
    const float* Wrx = (const float*)d_in[7];
    const float* Wrh = (const float*)d_in[8];
    const float* Wd  = (const float*)d_in[9];
    float* out = (float*)d_out;

    char* ws = (char*)d_ws;
    const bool traj = (ws_size >= (size_t)WS_NEED_TRAJ);
    const int dslots = traj ? 257 : 2;

    unsigned* bar = (unsigned*)(ws + WS_BAR);
    char* xF  = ws + WS_X;
    char* WDF = ws + WS_WDF;
    char* dT  = ws + WS_D;
    char* hT  = dT + (size_t)dslots * D_SLOT;

    prep_x<<<4096, 256, 0, stream>>>(x, xF);
    prep_wdf<<<64, 256, 0, stream>>>(Wd, WDF);
    prep_h0<<<32, 256, 0, stream>>>(h0, hT, bar);
    prep_d0<<<4, 256, 0, stream>>>(d0, dT);

    if (traj)
        sclstm_main<true><<<NBLK, NTHR, 0, stream>>>(xF, WDF, hT, dT, Wx, Wh, Wrx, Wrh,
                                                     bv, c0, d0, out, bar);
    else
        sclstm_main<false><<<NBLK, NTHR, 0, stream>>>(xF, WDF, hT, dT, Wx, Wh, Wrx, Wrh,
                                                      bv, c0, d0, out, bar);
}

// Round 5
// 2924.000 us; speedup vs baseline: 6.2148x; 1.6106x over previous
//
#include <hip/hip_runtime.h>
#include <cstdint>

// ---------------------------------------------------------------------------
// SC-LSTM persistent kernel, MI355X (gfx950) — round 5.
//
//  vs round 4 (4.71 ms, ~18 us/step with ~3 us of work):
//  * RELAXED-only hot path. Round 4 used __ATOMIC_RELEASE fetch_adds for
//    every block every step; agent-scope release on gfx950 lowers to
//    s_waitcnt + buffer_wbl2 sc1 (full dirty-L2 writeback) -> ~16 us/step
//    serialized per XCD. Correctness is preserved without release: data
//    publishes are agent-scope write-through atomic stores, drained by
//    __syncthreads (vmcnt 0) BEFORE the relaxed counter add; visibility is
//    transitive through LLC-completed counter values.
//  * Split-phase barrier: arrive (relaxed add) -> compute next step's
//    x-part GEMM (h-independent) -> poll epoch mirror. Hides barrier
//    propagation behind useful work. K re-split: half0 = x 0..7 + h 16..31,
//    half1 = x 8..15 + h 32..47.
//  * Gate activations precomputed into registers before the d-wait.
//  Everything else identical to round 4 (split-precision fp16 MFMA, LDS-
//  resident weights, fragment-layout trajectories, hierarchical barrier).
// ---------------------------------------------------------------------------

#define TT   256
#define BB   64
#define IC   512
#define HC   1024
#define DC   100
#define NG   4096
#define NRB  7
#define NBLK 256
#define NTHR 512

typedef _Float16 f16;
typedef f16   f16x8 __attribute__((ext_vector_type(8)));
typedef float f32x4 __attribute__((ext_vector_type(4)));
typedef unsigned long long u64;

// ---- workspace layout (bytes) ----
#define WS_BAR   0ull                          // 8192 B of counters/mirrors
#define WS_X     8192ull                       // x A-frags: 1048576 * 32 B
#define WS_WDF   (WS_X + 33554432ull)          // Wd B-frags: 16384 * 32 B
#define WS_D     (WS_WDF + 524288ull)          // d A-frag slots
#define D_SLOT   32768ull
#define H_SLOT   262144ull
#define WS_NEED_TRAJ (WS_D + 257ull * D_SLOT + 257ull * H_SLOT)

// barrier word indices (spaced 64 uints = 256 B, all separate lines)
#define BAR_GRP(g)   (64 * (g))          // 8 group arrival counters
#define BAR_ROOT     512                 // root arrival counter
#define BAR_EPOCH(g) (576 + 64 * (g))    // 8 epoch mirrors
#define BAR_DCNT     1088                // d-producer counter
#define BAR_DEP(g)   (1152 + 64 * (g))   // 8 depoch mirrors

#define OFF_H  ((size_t)TT * BB * HC)
#define OFF_C  (OFF_H + (size_t)BB * HC)
#define OFF_D  (OFF_H + 2ull * BB * HC)

// ------------------------------------------------------------- helpers

__device__ __forceinline__ void split(float v, f16& hi, f16& lo) {
    hi = (f16)v;
    lo = (f16)(v - (float)hi);
}

__device__ __forceinline__ float fast_sigmoid(float x) {
    return 1.0f / (1.0f + __expf(-x));
}
__device__ __forceinline__ float fast_tanh(float x) {
    float ax = fabsf(x);
    float e  = __expf(-2.0f * ax);
    float r  = (1.0f - e) / (1.0f + e);
    return copysignf(r, x);
}

__device__ __forceinline__ void astore8(char* p, u64 v) {
    __hip_atomic_store((u64*)p, v, __ATOMIC_RELAXED, __HIP_MEMORY_SCOPE_AGENT);
}
__device__ __forceinline__ void astore4(unsigned* p, unsigned v) {
    __hip_atomic_store(p, v, __ATOMIC_RELAXED, __HIP_MEMORY_SCOPE_AGENT);
}
__device__ __forceinline__ unsigned aload4(const unsigned* p) {
    return __hip_atomic_load(p, __ATOMIC_RELAXED, __HIP_MEMORY_SCOPE_AGENT);
}
__device__ __forceinline__ unsigned aadd4(unsigned* p) {
    return __hip_atomic_fetch_add(p, 1u, __ATOMIC_RELAXED, __HIP_MEMORY_SCOPE_AGENT);
}

// 32B A-frag load (hi 16B + lo 16B). TRAJ: normal cached. else: L2-bypass.
template <bool TRAJ>
__device__ __forceinline__ void loadAB(const char* p, f16x8& hi, f16x8& lo) {
    if constexpr (TRAJ) {
        hi = *(const f16x8*)p;
        lo = *(const f16x8*)(p + 16);
    } else {
        union { u64 q[2]; f16x8 v; } a, b;
        const u64* q = (const u64*)p;
        a.q[0] = __hip_atomic_load(q + 0, __ATOMIC_RELAXED, __HIP_MEMORY_SCOPE_AGENT);
        a.q[1] = __hip_atomic_load(q + 1, __ATOMIC_RELAXED, __HIP_MEMORY_SCOPE_AGENT);
        b.q[0] = __hip_atomic_load(q + 2, __ATOMIC_RELAXED, __HIP_MEMORY_SCOPE_AGENT);
        b.q[1] = __hip_atomic_load(q + 3, __ATOMIC_RELAXED, __HIP_MEMORY_SCOPE_AGENT);
        hi = a.v; lo = b.v;
    }
}

// ------------------------------------------------------------- prep kernels

__global__ void prep_x(const float* __restrict__ x, char* __restrict__ xF) {
    const int i = blockIdx.x * blockDim.x + threadIdx.x;   // < 1048576
    const int lane = i & 63, ks = (i >> 6) & 15, rg = (i >> 10) & 3, t = i >> 12;
    const int m = lane & 15, quad = lane >> 4;
    const float* src = x + (size_t)(t * BB + rg * 16 + m) * IC + ks * 32 + quad * 8;
    f16 hi[8], lo[8];
#pragma unroll
    for (int j = 0; j < 8; ++j) split(src[j], hi[j], lo[j]);
    char* dst = xF + (size_t)i * 32;
    *(f16x8*)dst        = *(f16x8*)hi;
    *(f16x8*)(dst + 16) = *(f16x8*)lo;
}

__global__ void prep_wdf(const float* __restrict__ Wd, char* __restrict__ WDF) {
    const int i = blockIdx.x * blockDim.x + threadIdx.x;   // < 16384
    const int lane = i & 63, kd = (i >> 6) & 3, s = i >> 8;
    const int n = lane & 15, quad = lane >> 4;
    f16 hi[8], lo[8];
#pragma unroll
    for (int j = 0; j < 8; ++j) {
        const int k = kd * 32 + quad * 8 + j;
        const float v = (k < DC) ? Wd[(size_t)k * HC + 16 * s + n] : 0.0f;
        split(v, hi[j], lo[j]);
    }
    char* dst = WDF + (size_t)i * 32;
    *(f16x8*)dst        = *(f16x8*)hi;
    *(f16x8*)(dst + 16) = *(f16x8*)lo;
}

__global__ void prep_h0(const float* __restrict__ h0, char* __restrict__ hT,
                        unsigned* __restrict__ bar) {
    const int i = blockIdx.x * blockDim.x + threadIdx.x;   // < 8192
    const int lane = i & 63, ks = (i >> 6) & 31, rg = i >> 11;
    const int m = lane & 15, quad = lane >> 4;
    const float* src = h0 + (size_t)(rg * 16 + m) * HC + ks * 32 + quad * 8;
    f16 hi[8], lo[8];
#pragma unroll
    for (int j = 0; j < 8; ++j) split(src[j], hi[j], lo[j]);
    char* dst = hT + (size_t)i * 32;
    *(f16x8*)dst        = *(f16x8*)hi;
    *(f16x8*)(dst + 16) = *(f16x8*)lo;
    if (i < 2048) bar[i] = 0u;
}

__global__ void prep_d0(const float* __restrict__ d0, char* __restrict__ dT) {
    const int i = blockIdx.x * blockDim.x + threadIdx.x;   // < 1024
    const int lane = i & 63, kd = (i >> 6) & 3, rg = i >> 8;
    const int m = lane & 15, quad = lane >> 4;
    f16 hi[8], lo[8];
#pragma unroll
    for (int j = 0; j < 8; ++j) {
        const int k = kd * 32 + quad * 8 + j;
        const float v = (k < DC) ? d0[(size_t)(rg * 16 + m) * DC + k] : 0.0f;
        split(v, hi[j], lo[j]);
    }
    char* dst = dT + (size_t)i * 32;
    *(f16x8*)dst        = *(f16x8*)hi;
    *(f16x8*)(dst + 16) = *(f16x8*)lo;
}

// ------------------------------------------------------------- GEMM pieces

#define MFMA16(a, b, c) __builtin_amdgcn_mfma_f32_16x16x32_f16((a), (b), (c), 0, 0, 0)

// x-part: ks in [half*8, half*8+8), normal cached loads, accs zero-inited.
__device__ __forceinline__ void xpart_gemm(
    const char* __restrict__ xb, const f16* __restrict__ BFH,
    const f16* __restrict__ BFL, const f16* __restrict__ RBF,
    int half, int lane, bool withr,
    f32x4& ghh, f32x4& ghl, f32x4& glh, f32x4& rh, f32x4& rl) {
    ghh = f32x4{0,0,0,0}; ghl = f32x4{0,0,0,0}; glh = f32x4{0,0,0,0};
    rh  = f32x4{0,0,0,0}; rl  = f32x4{0,0,0,0};
    const int k0 = half * 8;
#pragma unroll
    for (int i = 0; i < 8; ++i) {
        const int ks = k0 + i;
        const char* ap = xb + (size_t)(ks * 64 + lane) * 32;
        f16x8 ah = *(const f16x8*)ap;
        f16x8 al = *(const f16x8*)(ap + 16);
        f16x8 bh = *(const f16x8*)(BFH + (ks * 64 + lane) * 8);
        f16x8 bl = *(const f16x8*)(BFL + (ks * 64 + lane) * 8);
        ghh = MFMA16(ah, bh, ghh);
        ghl = MFMA16(ah, bl, ghl);
        glh = MFMA16(al, bh, glh);
        if (withr) {
            f16x8 rb = *(const f16x8*)(RBF + (ks * 64 + lane) * 8);
            rh = MFMA16(ah, rb, rh);
            rl = MFMA16(al, rb, rl);
        }
    }
}

// h-part: ks in [16+half*16, 16+half*16+16), trajectory loads.
template <bool TRAJ>
__device__ __forceinline__ void hpart_gemm(
    const char* __restrict__ hb, const f16* __restrict__ BFH,
    const f16* __restrict__ BFL, const f16* __restrict__ RBF,
    int half, int lane, bool withr,
    f32x4& ghh, f32x4& ghl, f32x4& glh, f32x4& rh, f32x4& rl) {
    const int k0 = 16 + half * 16;
#pragma unroll
    for (int i = 0; i < 16; ++i) {
        const int ks = k0 + i;
        f16x8 ah, al;
        loadAB<TRAJ>(hb + (size_t)((ks - 16) * 64 + lane) * 32, ah, al);
        f16x8 bh = *(const f16x8*)(BFH + (ks * 64 + lane) * 8);
        f16x8 bl = *(const f16x8*)(BFL + (ks * 64 + lane) * 8);
        ghh = MFMA16(ah, bh, ghh);
        ghl = MFMA16(ah, bl, ghl);
        glh = MFMA16(al, bh, glh);
        if (withr) {
            f16x8 rb = *(const f16x8*)(RBF + (ks * 64 + lane) * 8);
            rh = MFMA16(ah, rb, rh);
            rl = MFMA16(al, rb, rl);
        }
    }
}

// ------------------------------------------------------------- main kernel

template <bool TRAJ>
__global__ __launch_bounds__(NTHR) void sclstm_main(
    const char* __restrict__ xF, const char* __restrict__ WDF,
    char* hT, char* dT,
    const float* __restrict__ Wx, const float* __restrict__ Wh,
    const float* __restrict__ Wrx, const float* __restrict__ Wrh,
    const float* __restrict__ bvec, const float* __restrict__ c0,
    const float* __restrict__ d0, float* __restrict__ out,
    unsigned* bar) {

    const int g    = blockIdx.x;
    const int grp  = g & 7;
    const int tid  = threadIdx.x;
    const int w    = tid >> 6;
    const int half = w >> 2;                // K split
    const int wrow = w & 3;                 // 16-row A tile
    const int lane = tid & 63;
    const int n    = lane & 15;
    const int quad = lane >> 4;
    const bool withr = (g < NRB);

    // LDS map (155,904 B total)
    __shared__ __align__(16) char smem[155904];
    f16*  BFH = (f16*)(smem);                               // [48][64][8] gate B hi
    f16*  BFL = (f16*)(smem + 49152);                       // [48][64][8] gate B lo
    f16*  RBF = (f16*)(smem + 98304);                       // [48][64][8] r B hi
    float (*GL)[17]    = (float(*)[17])(smem + 147456);     // [64][17] gate preacts
    float (*TST)[16]   = (float(*)[16])(smem + 147456);     // stage (overlay GL)
    f32x4* PART        = (f32x4*)(smem + 151808);           // [4][64] split-K partials
    f16 (*DST)[32][16] = (f16(*)[32][16])(smem + 151808);   // [4][32][16] d stage
    float (*DAL)[5]    = (float(*)[5])(smem + 151808);      // [64][5] (overlay DST)
    f16 (*HST)[16][8]  = (f16(*)[16][8])(smem + 151808 + 1280); // [4][16][8] h stage

    // ---------------- one-time: gate B-frags in LDS (2 ks rows per iter)
    for (int ks2 = 0; ks2 < 24; ++ks2) {
        if (tid < 256) {
            const int krow = tid >> 2, q = tid & 3;
            const int k = ks2 * 64 + krow;
            const float* W = (k < IC) ? (Wx + (size_t)k * NG)
                                      : (Wh + (size_t)(k - IC) * NG);
            const float4 v = *(const float4*)(W + q * HC + 4 * g);
            TST[krow][q * 4 + 0] = v.x; TST[krow][q * 4 + 1] = v.y;
            TST[krow][q * 4 + 2] = v.z; TST[krow][q * 4 + 3] = v.w;
        }
        __syncthreads();
#pragma unroll
        for (int e2 = 0; e2 < 2; ++e2) {
            const int e = tid * 2 + e2;             // 0..1023
            const int ksl = e >> 9, le = (e >> 3) & 63, j = e & 7;
            const float v = TST[ksl * 32 + (le >> 4) * 8 + j][le & 15];
            f16 hi, lo; split(v, hi, lo);
            const int ks = ks2 * 2 + ksl;
            BFH[(ks * 64 + le) * 8 + j] = hi;
            BFL[(ks * 64 + le) * 8 + j] = lo;
        }
        __syncthreads();
    }
    // one-time: r B-frags (hi only, alpha folded)
    if (withr) {
        for (int ks2 = 0; ks2 < 24; ++ks2) {
            if (tid < 256) {
                const int krow = tid >> 2, cg = tid & 3;
                const int k = ks2 * 64 + krow;
                const int col0 = 16 * g + cg * 4;
                float4 v = make_float4(0.f, 0.f, 0.f, 0.f);
                if (col0 < DC) {
                    if (k < IC) v = *(const float4*)(Wrx + (size_t)k * DC + col0);
                    else {
                        float4 u = *(const float4*)(Wrh + (size_t)(k - IC) * DC + col0);
                        v = make_float4(0.5f * u.x, 0.5f * u.y, 0.5f * u.z, 0.5f * u.w);
                    }
                }
                TST[krow][cg * 4 + 0] = v.x; TST[krow][cg * 4 + 1] = v.y;
                TST[krow][cg * 4 + 2] = v.z; TST[krow][cg * 4 + 3] = v.w;
            }
            __syncthreads();
#pragma unroll
            for (int e2 = 0; e2 < 2; ++e2) {
                const int e = tid * 2 + e2;
                const int ksl = e >> 9, le = (e >> 3) & 63, j = e & 7;
                const int ks = ks2 * 2 + ksl;
                RBF[(ks * 64 + le) * 8 + j] = (f16)TST[ksl * 32 + (le >> 4) * 8 + j][le & 15];
            }
            __syncthreads();
        }
    }

    // ---------------- per-thread state
    const float biasv = bvec[(n >> 2) * HC + g * 4 + (n & 3)];
    const int row2 = tid >> 2, jj = tid & 3;        // valid for tid < 256
    float c = 0.f;
    if (tid < 256) c = c0[(size_t)row2 * HC + 4 * g + jj];
    float d_prev[4] = {0.f, 0.f, 0.f, 0.f};
    if (withr && half == 0 && 16 * g + n < DC) {
#pragma unroll
        for (int r = 0; r < 4; ++r)
            d_prev[r] = d0[(size_t)(wrow * 16 + quad * 4 + r) * DC + 16 * g + n];
    }
    __syncthreads();

    const int ksh = g >> 3, qkh = (g & 7) >> 1, jw = (g & 1) * 4;   // h-frag coords

    // prime accumulators with x-part of step 0
    f32x4 ghh, ghl, glh, rh, rl;
    xpart_gemm(xF + (size_t)wrow * 32768, BFH, BFL, RBF, half, lane, withr,
               ghh, ghl, glh, rh, rl);

    // ---------------- time loop
    for (int t = 0; t < TT; ++t) {
        const int slH  = TRAJ ? t : (t & 1);
        const int slH1 = TRAJ ? (t + 1) : ((t + 1) & 1);
        const int slD1 = slH1;

        // ---- phase 1: h-part GEMM (x-part already accumulated) ----
        hpart_gemm<TRAJ>(hT + (size_t)slH * H_SLOT + (size_t)wrow * 65536,
                         BFH, BFL, RBF, half, lane, withr, ghh, ghl, glh, rh, rl);
        f32x4 accg = ghh + ghl + glh;
        f32x4 accr = rh + rl;

        // ---- split-K reduction (gate) ----
        if (half == 1) PART[wrow * 64 + lane] = accg;
        __syncthreads();
        if (half == 0) accg += PART[wrow * 64 + lane];
        // ---- split-K reduction (r, r-blocks only) ----
        if (withr) {
            __syncthreads();
            if (half == 1) PART[wrow * 64 + lane] = accr;
            __syncthreads();
            if (half == 0) accr += PART[wrow * 64 + lane];
        }

        // ---- phase 2: gate preacts -> LDS ----
        if (half == 0) {
#pragma unroll
            for (int r = 0; r < 4; ++r)
                GL[wrow * 16 + quad * 4 + r][n] = accg[r] + biasv;
        }

        // ---- phase 3 (blocks 0..6): d update + publish ----
        if (withr) {
            if (half == 0) {
#pragma unroll
                for (int r = 0; r < 4; ++r) {
                    const float rv = fast_sigmoid(accr[r]);
                    const float dn = rv * d_prev[r];
                    d_prev[r] = dn;
                    f16 hi, lo; split(dn, hi, lo);
                    const int sr = (n >> 3) * 16 + quad * 4 + r;
                    DST[wrow][sr][n & 7]       = hi;
                    DST[wrow][sr][8 + (n & 7)] = lo;
                }
                if (t == TT - 1 && 16 * g + n < DC) {
#pragma unroll
                    for (int r = 0; r < 4; ++r)
                        out[OFF_D + (size_t)(wrow * 16 + quad * 4 + r) * DC + 16 * g + n] = d_prev[r];
                }
            }
            __syncthreads();
            if (tid < 256) {
                const int rg = tid >> 6, l32 = (tid >> 1) & 31, part = tid & 1;
                char* base = dT + (size_t)slD1 * D_SLOT;
                char* dp = base + (size_t)((rg * 4 + (g >> 1)) * 64 + 32 * (g & 1) + l32) * 32
                           + part * 8;
                astore8(dp,      *(const u64*)&DST[rg][l32][part * 4]);
                astore8(dp + 16, *(const u64*)&DST[rg][l32][8 + part * 4]);
                if (g == 6) {   // zero-fill d-frag cols 112..127
                    char* zp = base + (size_t)((rg * 4 + 3) * 64 + 32 + l32) * 32 + part * 8;
                    astore8(zp, 0ull); astore8(zp + 16, 0ull);
                }
            }
            __syncthreads();   // drain d stores (vmcnt 0) before relaxed signal
            if (tid == 0) {
                unsigned o = aadd4(bar + BAR_DCNT);
                if (o % NRB == NRB - 1) {   // last d producer this step
#pragma unroll
                    for (int e = 0; e < 8; ++e) astore4(bar + BAR_DEP(e), t + 1);
                }
            }
        } else {
            __syncthreads();   // make GL visible for activation precompute
        }

        // ---- precompute gate activations (off the post-d-wait path) ----
        float iv = 0.f, fv = 0.f, gv = 0.f, ov = 0.f;
        if (tid < 256) {
            iv = fast_sigmoid(GL[row2][jj]);
            fv = fast_sigmoid(GL[row2][4 + jj]);
            gv = fast_tanh(GL[row2][8 + jj]);
            ov = fast_sigmoid(GL[row2][12 + jj]);
        }

        // ---- phase 4: wait for d-ready broadcast ----
        if (tid == 0) {
            while (aload4(bar + BAR_DEP(grp)) < (unsigned)(t + 1))
                __builtin_amdgcn_s_sleep(1);
        }
        __syncthreads();

        // ---- phase 5: da = d_new @ Wd (K=128, split precision) ----
        if (half == 0) {
            f32x4 da = {0,0,0,0};
            const char* db = dT + (size_t)slD1 * D_SLOT + (size_t)wrow * 8192;
            const char* wb = WDF + (size_t)(g >> 2) * 8192;
#pragma unroll
            for (int kd = 0; kd < 4; ++kd) {
                f16x8 dh, dl;
                loadAB<TRAJ>(db + (size_t)(kd * 64 + lane) * 32, dh, dl);
                const char* wp = wb + (size_t)(kd * 64 + lane) * 32;
                f16x8 wh = *(const f16x8*)wp;
                f16x8 wl = *(const f16x8*)(wp + 16);
                da = MFMA16(dh, wh, da);
                da = MFMA16(dh, wl, da);
                da = MFMA16(dl, wh, da);
            }
            const int wo = n - 4 * (g & 3);
            if ((unsigned)wo < 4u) {
#pragma unroll
                for (int r = 0; r < 4; ++r)
                    DAL[wrow * 16 + quad * 4 + r][wo] = da[r];
            }
        }
        __syncthreads();

        // ---- phase 6: c/h update (1 state/thread, threads 0..255) ----
        if (tid < 256) {
            c = fv * c + iv * gv + fast_tanh(DAL[row2][jj]);
            const float h = ov * fast_tanh(c);
            out[((size_t)t * BB + row2) * HC + 4 * g + jj] = h;
            f16 hh_, hl_; split(h, hh_, hl_);
            HST[row2 >> 4][row2 & 15][jj]     = hh_;
            HST[row2 >> 4][row2 & 15][4 + jj] = hl_;
            if (t == TT - 1) {
                out[OFF_H + (size_t)row2 * HC + 4 * g + jj] = h;
                out[OFF_C + (size_t)row2 * HC + 4 * g + jj] = c;
            }
        }
        __syncthreads();

        // ---- phase 7: publish h fragment (coalesced 8B stores) ----
        if (tid < 128) {
            const int rg = tid >> 5, m = (tid >> 1) & 15, hlf = tid & 1;
            const u64 v = *(const u64*)&HST[rg][m][hlf * 4];
            char* p = hT + (size_t)slH1 * H_SLOT
                      + (size_t)((rg * 32 + ksh) * 64 + qkh * 16 + m) * 32
                      + hlf * 16 + jw * 2;
            astore8(p, v);
        }
        __syncthreads();   // drain h stores (vmcnt 0) before relaxed arrival

        // ---- phase 8: split-phase hierarchical barrier ----
        if (tid == 0) {
            unsigned o = aadd4(bar + BAR_GRP(grp));
            if ((o & 31) == 31) {           // last in group
                unsigned o2 = aadd4(bar + BAR_ROOT);
                if ((o2 & 7) == 7) {        // last overall: broadcast epoch
#pragma unroll
                    for (int e = 0; e < 8; ++e) astore4(bar + BAR_EPOCH(e), t + 1);
                }
            }
        }

        // ---- overlap: x-part GEMM of step t+1 while epoch propagates ----
        if (t + 1 < TT) {
            xpart_gemm(xF + (size_t)((t + 1) * 4 + wrow) * 32768,
                       BFH, BFL, RBF, half, lane, withr, ghh, ghl, glh, rh, rl);
        }

        if (tid == 0) {
            while (aload4(bar + BAR_EPOCH(grp)) < (unsigned)(t + 1))
                __builtin_amdgcn_s_sleep(2);
        }
        __syncthreads();
    }
}

// ------------------------------------------------------------- launch

extern "C" void kernel_launch(void* const* d_in, const int* in_sizes, int n_in,
                              void* d_out, int out_size, void* d_ws, size_t ws_size,
                              hipStream_t stream) {
    const float* x   = (const float*)d_in[0];
    const float* h0  = (const float*)d_in[1];
    const float* c0  = (const float*)d_in[2];
    const float* d0  = (const float*)d_in[3];
    const float* Wx  = (const float*)d_in[4];
    const float* Wh  = (const float*)d_in[5];
    const float* bv  = (const float*)d_in[6];
    const float* Wrx = (const float*)d_in[7];
    const float* Wrh = (const float*)d_in[8];
    const float* Wd  = (const float*)d_in[9];
    float* out = (float*)d_out;

    char* ws = (char*)d_ws;
    const bool traj = (ws_size >= (size_t)WS_NEED_TRAJ);
    const int dslots = traj ? 257 : 2;

    unsigned* bar = (unsigned*)(ws + WS_BAR);
    char* xF  = ws + WS_X;
    char* WDF = ws + WS_WDF;
    char* dT  = ws + WS_D;
    char* hT  = dT + (size_t)dslots * D_SLOT;

    prep_x<<<4096, 256, 0, stream>>>(x, xF);
    prep_wdf<<<64, 256, 0, stream>>>(Wd, WDF);
    prep_h0<<<32, 256, 0, stream>>>(h0, hT, bar);
    prep_d0<<<4, 256, 0, stream>>>(d0, dT);

    if (traj)
        sclstm_main<true><<<NBLK, NTHR, 0, stream>>>(xF, WDF, hT, dT, Wx, Wh, Wrx, Wrh,
                                                     bv, c0, d0, out, bar);
    else
        sclstm_main<false><<<NBLK, NTHR, 0, stream>>>(xF, WDF, hT, dT, Wx, Wh, Wrx, Wrh,
                                                      bv, c0, d0, out, bar);
}